// Round 5
// baseline (598.453 us; speedup 1.0000x reference)
//
#include <hip/hip_runtime.h>
#include <hip/hip_bf16.h>

#define BB 32
#define LL 200
#define DD 768
#define SS 1556
#define MAXM 6400   // per-kk flattened row capacity (32 * (199-kk) < 6400)

typedef __attribute__((ext_vector_type(8))) short bf16x8;   // 8 bf16 = 4 VGPRs (MFMA A/B frag)
typedef __attribute__((ext_vector_type(4))) float floatx4;  // MFMA C/D frag

__device__ __forceinline__ float bf2f(ushort u){
    union { unsigned int i; float f; } v; v.i = ((unsigned int)u) << 16; return v.f;
}
__device__ __forceinline__ ushort f2bf(float f){
    union { float f; unsigned int i; } v; v.f = f;
    unsigned int x = v.i;
    return (ushort)((x + 0x7FFFu + ((x >> 16) & 1u)) >> 16);  // RNE, inputs finite
}

// XCD schedule tables in .rodata (scalar-loaded; runtime-indexed local arrays
// would go to scratch per rule #20).
__device__ const int GCNT_C[8] = {5,5,5,5,5,5,6,6};
__device__ const int GLIST_C[8][6] = {
    {36,37,38, 0, 4, 0},   // kk8 x3 + kk2 x2
    {39,40,41, 1, 5, 0},   // kk8 x3 + kk2 x2
    {30,31,32, 6, 2, 0},   // kk7 x3 + kk3 + kk2
    {33,34,35, 7, 3, 0},   // kk7 x3 + kk3 + kk2
    {24,25,26,12,13, 0},   // kk6 x3 + kk4 x2
    {27,28,29,14,15, 0},   // kk6 x3 + kk4 x2
    {18,19,20,16, 8,10},   // kk5 x3 + kk4 + kk3 x2
    {21,22,23,17, 9,11},   // kk5 x3 + kk4 + kk3 x2
};

// ---------------------------------------------------------------------------
// Kernel 0: dtype detector (flag=1 -> bf16 data, flag=0 -> float32).
// ---------------------------------------------------------------------------
__global__ void detect_kernel(const unsigned int* __restrict__ feat_raw, int* __restrict__ flag){
    __shared__ int cnt_s;
    if (threadIdx.x == 0) cnt_s = 0;
    __syncthreads();
    int c = 0;
    for (int i = threadIdx.x; i < 4096; i += 256){
        unsigned int w = feat_raw[i];
        unsigned int e = (w >> 7) & 0xFFu;
        if (e >= 100u && e <= 150u) c++;
    }
    atomicAdd(&cnt_s, c);
    __syncthreads();
    if (threadIdx.x == 0) *flag = (cnt_s > 2457) ? 1 : 0;
}

// ---------------------------------------------------------------------------
// Kernel 1: per-batch span offsets. offs[b][0..8]; counts[k] = max(n-k-2, 0).
// ---------------------------------------------------------------------------
__global__ void offs_kernel(const int* __restrict__ mask, int* __restrict__ offs){
    int b = blockIdx.x;
    int lane = threadIdx.x;
    int s = 0;
    for (int i = lane; i < LL; i += 64) s += mask[b*LL + i];
    #pragma unroll
    for (int d = 32; d > 0; d >>= 1) s += __shfl_down(s, d, 64);
    if (lane == 0){
        int n = s, cum = 0;
        offs[b*9 + 0] = 0;
        for (int j = 0; j < 8; ++j){
            int c = n - j - 2; if (c < 0) c = 0;
            cum += c;
            offs[b*9 + j + 1] = cum;
        }
    }
}

// ---------------------------------------------------------------------------
// Kernel 1b: flattened-M row maps per width bucket.
// ---------------------------------------------------------------------------
__global__ void maps_kernel(const int* __restrict__ offs, int* __restrict__ pfx,
                            int* __restrict__ amap, int* __restrict__ omap){
    const int kkidx = blockIdx.x;
    const int kk = kkidx + 2;
    __shared__ int P[33];
    __shared__ int base_s[32];
    const int tid = threadIdx.x;
    if (tid == 0){
        int acc = 0; P[0] = 0;
        for (int b = 0; b < 32; ++b){
            acc += offs[b*9 + kk] - offs[b*9 + kk - 1];
            P[b+1] = acc;
        }
    }
    if (tid < 32) base_s[tid] = offs[tid*9 + kk - 1];
    __syncthreads();
    if (tid == 0) pfx[kkidx*33 + 32] = P[32];
    const int Mtot = P[32];
    for (int r = tid; r < MAXM; r += 256){
        int b = 0;
        #pragma unroll
        for (int i = 1; i <= 32; ++i) b += (P[i] <= r) ? 1 : 0;
        int bb = b < 32 ? b : 31;
        int larow = (r < Mtot) ? (r - P[bb]) : 0;   // clamp OOB rows to a safe row
        amap[kkidx*MAXM + r] = bb*LL + larow + 1;
        omap[kkidx*MAXM + r] = bb*SS + base_s[bb] + larow;
    }
}

// ---------------------------------------------------------------------------
// Kernel 2: ALL widths' weight repack in ONE launch. grid=(192, 7).
// ---------------------------------------------------------------------------
__global__ void repack2_kernel(const void* __restrict__ w2, const void* __restrict__ w3,
                               const void* __restrict__ w4, const void* __restrict__ w5,
                               const void* __restrict__ w6, const void* __restrict__ w7,
                               const void* __restrict__ w8,
                               const void* __restrict__ b2, const void* __restrict__ b3,
                               const void* __restrict__ b4, const void* __restrict__ b5,
                               const void* __restrict__ b6, const void* __restrict__ b7,
                               const void* __restrict__ b8,
                               ushort* __restrict__ BpAll, float* __restrict__ biasF,
                               const int* __restrict__ flag){
    const int kkidx = blockIdx.y;
    const int kk = kkidx + 2;
    const void* w  = kkidx==0?w2:kkidx==1?w3:kkidx==2?w4:kkidx==3?w5:kkidx==4?w6:kkidx==5?w7:w8;
    const void* bv = kkidx==0?b2:kkidx==1?b3:kkidx==2?b4:kkidx==3?b5:kkidx==4?b6:kkidx==5?b7:b8;
    ushort* Bp = BpAll + (size_t)(kkidx*(kkidx+3)/2)*589824;   // PRE[kkidx]

    const int bfm = *flag;
    __shared__ ushort lds[24576];         // 4 rows x 768*8 max (49152 B)
    const int tid = threadIdx.x;
    const int ob  = blockIdx.x;           // 4 output channels each
    const int rowlen = DD * kk;
    const int nelem  = 4 * rowlen;

    if (bfm){
        const ushort* src = (const ushort*)w + (size_t)ob * nelem;
        const int nch = nelem >> 3;
        for (int c = tid; c < nch; c += 256)
            __builtin_memcpy(lds + c*8, src + c*8, 16);
        if (ob == 0)
            for (int i = tid; i < DD; i += 256) biasF[kkidx*DD + i] = bf2f(((const ushort*)bv)[i]);
    } else {
        const float* src = (const float*)w + (size_t)ob * nelem;
        const int nch = nelem >> 2;
        for (int c = tid; c < nch; c += 256){
            float t4[4];
            __builtin_memcpy(t4, src + c*4, 16);
            #pragma unroll
            for (int j2 = 0; j2 < 4; ++j2) lds[c*4 + j2] = f2bf(t4[j2]);
        }
        if (ob == 0)
            for (int i = tid; i < DD; i += 256) biasF[kkidx*DD + i] = ((const float*)bv)[i];
    }
    __syncthreads();

    const int total = 96 * kk * 4;
    for (int c = tid; c < total; c += 256){
        int jb = c >> 2, ol = c & 3;
        int j0 = jb * 8;
        int t  = j0 / 768;
        int i0 = j0 - t * 768;
        ushort tmp[8];
        #pragma unroll
        for (int jj = 0; jj < 8; ++jj)
            tmp[jj] = lds[ol*rowlen + (i0 + jj)*kk + t];
        int o = ob*4 + ol;
        __builtin_memcpy(Bp + (size_t)jb*6144 + (size_t)o*8, tmp, 16);
    }
}

// ---------------------------------------------------------------------------
// Kernel 2b: features -> bf16 A-source buffer.
// ---------------------------------------------------------------------------
__global__ void cvtA_kernel(const void* __restrict__ feat, ushort* __restrict__ featbf,
                            const int* __restrict__ flag){
    const int bfm = *flag;
    int idx = blockIdx.x*256 + threadIdx.x;
    const int TOT = BB*LL*DD/8;
    if (idx >= TOT) return;
    if (bfm){
        __builtin_memcpy(featbf + (size_t)idx*8, (const ushort*)feat + (size_t)idx*8, 16);
    } else {
        float t8[8];
        __builtin_memcpy(t8,     (const float*)feat + (size_t)idx*8,     16);
        __builtin_memcpy(t8 + 4, (const float*)feat + (size_t)idx*8 + 4, 16);
        ushort o8[8];
        #pragma unroll
        for (int j = 0; j < 8; ++j) o8[j] = f2bf(t8[j]);
        __builtin_memcpy(featbf + (size_t)idx*8, o8, 16);
    }
}

// ---------------------------------------------------------------------------
// Kernel 3: unigram copy + zero invalid + valid flags (native dtype).
// ---------------------------------------------------------------------------
__global__ void fill_kernel(const void* __restrict__ feat, const int* __restrict__ offs,
                            void* __restrict__ out, const int* __restrict__ flag){
    const int bfm = *flag;
    int idx = blockIdx.x*256 + threadIdx.x;
    const int TOT = BB*SS*192;
    if (idx >= TOT) return;
    int b = idx / (SS*192);
    int r = idx - b*(SS*192);
    int s = r / 192;
    int c = r - s*192;
    int c0  = offs[b*9 + 1];
    int tot = offs[b*9 + 8];
    if (bfm){
        if (c < 96){
            ushort* dst = (ushort*)out + ((size_t)b*SS + s)*768 + c*8;
            if (s < c0){
                const ushort* srcp = (const ushort*)feat + ((size_t)b*LL + s + 1)*768 + c*8;
                __builtin_memcpy(dst, srcp, 16);
            } else if (s >= tot){
                const ushort z[8] = {0,0,0,0,0,0,0,0};
                __builtin_memcpy(dst, z, 16);
            }
        }
        if (c == 0)
            ((ushort*)out)[(size_t)BB*SS*768 + (size_t)b*SS + s] = (s < tot) ? (ushort)0x3F80 : (ushort)0;
    } else {
        float* dst = (float*)out + ((size_t)b*SS + s)*768 + c*4;
        if (s < c0){
            const float* srcp = (const float*)feat + ((size_t)b*LL + s + 1)*768 + c*4;
            __builtin_memcpy(dst, srcp, 16);
        } else if (s >= tot){
            const float z[4] = {0.f,0.f,0.f,0.f};
            __builtin_memcpy(dst, z, 16);
        }
        if (c == 0)
            ((float*)out)[(size_t)BB*SS*768 + (size_t)b*SS + s] = (s < tot) ? 1.0f : 0.0f;
    }
}

// ---------------------------------------------------------------------------
// Kernel 4 (v5): m97-structure GEMM — occupancy over explicit pipelining.
//  - Single-buffered A+B LDS (16+16 = 32 KB) -> 5 blocks/CU, 20 waves/CU.
//    Rounds 1-3 proved explicit pipelines (drain-0 / counted-vmcnt) are
//    worthless here; m97/m132 evidence says co-resident-block overlap is
//    what actually hides the stage latency (64 KB LDS = 2 blk/CU was the
//    m132 regression; 32 KB = 5 blk/CU is the m97 regime).
//  - Plain stage -> __syncthreads() -> compute -> __syncthreads() loop.
//  - A staged via global_load_lds in FRAGMENT order (round-4 win, kept).
//  - nt-pair-major XCD schedule (kept).
// ---------------------------------------------------------------------------
__global__ __launch_bounds__(256, 5) void conv_gemm6(const ushort* __restrict__ featbf,
        const ushort* __restrict__ BpAll, const float* __restrict__ biasF,
        const int* __restrict__ pfx, const int* __restrict__ amap,
        const int* __restrict__ omap, void* __restrict__ out,
        const int* __restrict__ flag){
    const int n   = blockIdx.x;
    const int xcd = n & 7;
    const int is  = n >> 3;
    const int cx  = GCNT_C[xcd];
    if (is >= cx * 50) return;
    // pair-major: consecutive slots alternate within a PAIR of groups so the
    // co-resident window covers only ~2 B-slices (L2-resident).
    int p = is / 100;
    int r = is - p*100;
    int gi, mt;
    if (2*p + 1 < cx){ gi = 2*p + (r & 1); mt = r >> 1; }
    else             { gi = 2*p;           mt = r;      }
    const int g  = GLIST_C[xcd][gi];
    const int kkidx = g / 6;
    const int nt = g - kkidx*6;
    const int kk = kkidx + 2;
    const int Mtot = pfx[kkidx*33 + 32];
    const int m0 = mt * 128;
    if (m0 >= Mtot) return;
    const int n0 = nt * 128;
    const int bfm = *flag;

    __shared__ ushort BsA[8192];           // 16 KB, fragment-ordered
    __shared__ ushort BsB[8192];           // 16 KB: 8 planes x 128 cols x 8

    const int tid  = threadIdx.x;
    const int wv   = tid >> 6;
    const int wvm  = wv >> 1;              // wave row (0..1)
    const int wvn  = wv & 1;               // wave col (0..1)
    const int lane = tid & 63;
    const int quad = lane >> 4;
    const int l15  = lane & 15;
    const int wvbase = tid & 192;          // wv*64 (wave-uniform)

    // A staging source pointers. Segment g2 = j*4+wv encodes (wvm,sm,ks):
    // g2 = wvm*8 + sm*2 + ks. Lane (quad,l15) supplies
    // featbf[amap(m0 + wvm*64 + sm*16 + l15)][ks*32 + quad*8 ..+8].
    const ushort* srcA[4];
    #pragma unroll
    for (int j = 0; j < 4; ++j){
        int g2 = j*4 + wv;
        int wvm_s = g2 >> 3, sm_s = (g2 >> 1) & 3, ks_s = g2 & 1;
        int rr = kkidx*MAXM + m0 + wvm_s*64 + sm_s*16 + l15;
        srcA[j] = featbf + (size_t)amap[rr]*768 + ks_s*32 + quad*8;
    }

    floatx4 acc[4][4];
    #pragma unroll
    for (int sn = 0; sn < 4; ++sn){
        float bv = biasF[kkidx*768 + n0 + wvn*64 + sn*16 + l15];
        #pragma unroll
        for (int sm = 0; sm < 4; ++sm){
            acc[sm][sn][0] = bv; acc[sm][sn][1] = bv;
            acc[sm][sn][2] = bv; acc[sm][sn][3] = bv;
        }
    }

    // B source: per-lane base; plane p = (tid>>7), col = n0 + (tid&127)
    const ushort* BkkBase = BpAll + (size_t)(kkidx*(kkidx+3)/2)*589824;
    const ushort* bsrc0 = BkkBase + (size_t)(tid >> 7)*6144 + (size_t)(n0 + (tid & 127))*8;
    char* ldsA = (char*)&BsA[0];
    char* ldsB = (char*)&BsB[0];
    const int nchunks = kk * 12;           // K / 64

    for (int ch = 0; ch < nchunks; ++ch){
        // ---- stage A (fragment order) + B (plane order): 8 gload_lds ----
        #pragma unroll
        for (int j = 0; j < 4; ++j){
            __builtin_amdgcn_global_load_lds(
                (const __attribute__((address_space(1))) void*)(srcA[j] + ch*64),
                (__attribute__((address_space(3))) void*)(ldsA + (j*256 + wvbase)*16),
                16, 0, 0);
        }
        {
            const ushort* gb = bsrc0 + (size_t)ch*8*6144;
            #pragma unroll
            for (int ii = 0; ii < 4; ++ii){
                __builtin_amdgcn_global_load_lds(
                    (const __attribute__((address_space(1))) void*)(gb + (size_t)ii*2*6144),
                    (__attribute__((address_space(3))) void*)(ldsB + (ii*256 + wvbase)*16),
                    16, 0, 0);
            }
        }
        __syncthreads();     // compiler emits s_waitcnt vmcnt(0) + s_barrier

        // ---- compute: 2 K-steps x 16 MFMA ----
        #pragma unroll
        for (int ks = 0; ks < 2; ++ks){
            const int pl = ks*4 + quad;
            bf16x8 afr[4], bfr[4];
            #pragma unroll
            for (int sm = 0; sm < 4; ++sm)
                __builtin_memcpy(&afr[sm], ldsA + (wvm*8 + sm*2 + ks)*1024 + lane*16, 16);
            #pragma unroll
            for (int sn = 0; sn < 4; ++sn)
                __builtin_memcpy(&bfr[sn], &BsB[pl*1024 + (wvn*64 + sn*16 + l15)*8], 16);
            #pragma unroll
            for (int sm = 0; sm < 4; ++sm)
                #pragma unroll
                for (int sn = 0; sn < 4; ++sn)
                    acc[sm][sn] = __builtin_amdgcn_mfma_f32_16x16x32_bf16(
                        afr[sm], bfr[sn], acc[sm][sn], 0, 0, 0);
        }
        __syncthreads();     // buffer reuse guard
    }

    // ---- epilogue: scatter rows to packed span slots ----
    #pragma unroll
    for (int sm = 0; sm < 4; ++sm){
        #pragma unroll
        for (int rr = 0; rr < 4; ++rr){
            int r2 = m0 + wvm*64 + sm*16 + quad*4 + rr;
            if (r2 < Mtot){
                int slot = omap[kkidx*MAXM + r2];
                if (bfm){
                    ushort* oh = (ushort*)out;
                    #pragma unroll
                    for (int sn = 0; sn < 4; ++sn)
                        oh[(size_t)slot*768 + n0 + wvn*64 + sn*16 + l15] = f2bf(acc[sm][sn][rr]);
                } else {
                    float* of = (float*)out;
                    #pragma unroll
                    for (int sn = 0; sn < 4; ++sn)
                        of[(size_t)slot*768 + n0 + wvn*64 + sn*16 + l15] = acc[sm][sn][rr];
                }
            }
        }
    }
}

// ---------------------------------------------------------------------------
// Fallback (workspace too small): direct-from-raw-weights GEMM. Slow, correct.
// ---------------------------------------------------------------------------
__global__ __launch_bounds__(256) void conv_gemm_direct(const void* __restrict__ feat,
        const int* __restrict__ offs, void* __restrict__ out, const int* __restrict__ flag,
        const void* w2, const void* w3, const void* w4, const void* w5,
        const void* w6, const void* w7, const void* w8,
        const void* b2, const void* b3, const void* b4, const void* b5,
        const void* b6, const void* b7, const void* b8){
    const int bfm = *flag;
    const int kkidx = blockIdx.y;
    const int kk = kkidx + 2;
    const int b = blockIdx.z;
    const void* w  = kkidx==0?w2:kkidx==1?w3:kkidx==2?w4:kkidx==3?w5:kkidx==4?w6:kkidx==5?w7:w8;
    const void* bv = kkidx==0?b2:kkidx==1?b3:kkidx==2?b4:kkidx==3?b5:kkidx==4?b6:kkidx==5?b7:b8;

    const int off_j = offs[b*9 + kk - 1];
    const int cnt   = offs[b*9 + kk] - off_j;
    const int mt = blockIdx.x / 12;
    const int nt = blockIdx.x - mt*12;
    const int m0 = mt * 64;
    if (m0 >= cnt) return;
    const int n0 = nt * 64;

    const int tid  = threadIdx.x;
    const int wvv  = tid >> 6;
    const int lane = tid & 63;
    const int quad = lane >> 4;
    const int l15  = lane & 15;

    int row  = m0 + wvv*16 + l15;
    int arow = row < cnt ? row : cnt - 1;
    const size_t abase = ((size_t)b*LL + arow + 1)*768 + quad*8;

    floatx4 acc[4];
    #pragma unroll
    for (int cg = 0; cg < 4; ++cg){
        float bb = bfm ? bf2f(((const ushort*)bv)[n0 + cg*16 + l15])
                       : ((const float*)bv)[n0 + cg*16 + l15];
        acc[cg][0] = bb; acc[cg][1] = bb; acc[cg][2] = bb; acc[cg][3] = bb;
    }

    const int steps = kk * 24;
    for (int s = 0; s < steps; ++s){
        bf16x8 a;
        if (bfm){
            __builtin_memcpy(&a, (const ushort*)feat + abase + s*32, 16);
        } else {
            float t8[8];
            __builtin_memcpy(t8,     (const float*)feat + abase + s*32,     16);
            __builtin_memcpy(t8 + 4, (const float*)feat + abase + s*32 + 4, 16);
            ushort o8[8];
            #pragma unroll
            for (int j = 0; j < 8; ++j) o8[j] = f2bf(t8[j]);
            __builtin_memcpy(&a, o8, 16);
        }
        int j0 = s*32 + quad*8;
        int t  = j0 / 768;
        int i0 = j0 - t*768;
        #pragma unroll
        for (int cg = 0; cg < 4; ++cg){
            int o = n0 + cg*16 + l15;
            size_t wbase = (size_t)o*(DD*kk) + (size_t)i0*kk + t;
            ushort tmp[8];
            if (bfm){
                const ushort* wp = (const ushort*)w + wbase;
                #pragma unroll
                for (int jj = 0; jj < 8; ++jj) tmp[jj] = wp[(size_t)jj*kk];
            } else {
                const float* wp = (const float*)w + wbase;
                #pragma unroll
                for (int jj = 0; jj < 8; ++jj) tmp[jj] = f2bf(wp[(size_t)jj*kk]);
            }
            bf16x8 bfr;
            __builtin_memcpy(&bfr, tmp, 16);
            acc[cg] = __builtin_amdgcn_mfma_f32_16x16x32_bf16(a, bfr, acc[cg], 0, 0, 0);
        }
    }

    const int rbase = m0 + wvv*16 + quad*4;
    if (bfm){
        ushort* outh = (ushort*)out;
        #pragma unroll
        for (int cg = 0; cg < 4; ++cg)
            #pragma unroll
            for (int rr = 0; rr < 4; ++rr){
                int grow = rbase + rr;
                if (grow < cnt)
                    outh[((size_t)b*SS + off_j + grow)*768 + n0 + cg*16 + l15] = f2bf(acc[cg][rr]);
            }
    } else {
        float* outf = (float*)out;
        #pragma unroll
        for (int cg = 0; cg < 4; ++cg)
            #pragma unroll
            for (int rr = 0; rr < 4; ++rr){
                int grow = rbase + rr;
                if (grow < cnt)
                    outf[((size_t)b*SS + off_j + grow)*768 + n0 + cg*16 + l15] = acc[cg][rr];
            }
    }
}

// ---------------------------------------------------------------------------
extern "C" void kernel_launch(void* const* d_in, const int* in_sizes, int n_in,
                              void* d_out, int out_size, void* d_ws, size_t ws_size,
                              hipStream_t stream) {
    const void* feat = d_in[0];
    const int*  mask = (const int*)d_in[1];

    const void* w[7]  = {0,0,0,0,0,0,0};
    const void* bs[7] = {0,0,0,0,0,0,0};
    int bi = 0;
    for (int i = 3; i < n_in; ++i){
        if (in_sizes[i] == 768){
            if (bi < 7) bs[bi++] = d_in[i];
        } else {
            int kk = in_sizes[i] / 589824;
            if (kk >= 2 && kk <= 8) w[kk-2] = d_in[i];
        }
    }

    // ws layout
    char* ws = (char*)d_ws;
    int*    flag    = (int*)ws;                       // @0
    int*    offs    = (int*)(ws + 64);                // 1152 B
    int*    pfx     = (int*)(ws + 2048);              // 924 B
    float*  biasF   = (float*)(ws + 4096);            // 21504 B
    int*    amap    = (int*)(ws + 28672);             // 7*6400*4 = 179200
    int*    omap    = (int*)(ws + 28672 + 179200);    // 179200 -> end 387072
    ushort* featbf  = (ushort*)(ws + 393216);         // 9,830,400
    ushort* Bp      = (ushort*)(ws + 393216 + 9830400); // 41,287,680
    const size_t FULL_BYTES = 393216ull + 9830400ull + 41287680ull;  // 51,511,296
    const bool use_full = ws_size >= FULL_BYTES;

    hipLaunchKernelGGL(detect_kernel, dim3(1), dim3(256), 0, stream,
                       (const unsigned int*)feat, flag);
    hipLaunchKernelGGL(offs_kernel, dim3(BB), dim3(64), 0, stream, mask, offs);

    if (use_full){
        hipLaunchKernelGGL(repack2_kernel, dim3(192, 7), dim3(256), 0, stream,
                           w[0], w[1], w[2], w[3], w[4], w[5], w[6],
                           bs[0], bs[1], bs[2], bs[3], bs[4], bs[5], bs[6],
                           Bp, biasF, flag);
        hipLaunchKernelGGL(cvtA_kernel, dim3(2400), dim3(256), 0, stream, feat, featbf, flag);
        hipLaunchKernelGGL(maps_kernel, dim3(7), dim3(256), 0, stream, offs, pfx, amap, omap);
    }

    hipLaunchKernelGGL(fill_kernel, dim3((BB*SS*192 + 255)/256), dim3(256), 0, stream,
                       feat, offs, d_out, flag);

    if (use_full){
        // 1D grid, 8 XCD classes x 300 slots (inactive slots exit immediately)
        hipLaunchKernelGGL(conv_gemm6, dim3(2400), dim3(256), 0, stream,
                           featbf, Bp, biasF, pfx, amap, omap, d_out, flag);
    } else {
        hipLaunchKernelGGL(conv_gemm_direct, dim3(48, 7, BB), dim3(256), 0, stream,
                           feat, offs, d_out, flag,
                           w[0], w[1], w[2], w[3], w[4], w[5], w[6],
                           bs[0], bs[1], bs[2], bs[3], bs[4], bs[5], bs[6]);
    }
}

// Round 6
// 563.899 us; speedup vs baseline: 1.0613x; 1.0613x over previous
//
#include <hip/hip_runtime.h>
#include <hip/hip_bf16.h>

#define BB 32
#define LL 200
#define DD 768
#define SS 1556
#define MAXM 6400   // per-kk flattened row capacity (25 tiles x 256 = 6400)

typedef __attribute__((ext_vector_type(8))) short bf16x8;   // 8 bf16 = 4 VGPRs (MFMA A/B frag)
typedef __attribute__((ext_vector_type(4))) float floatx4;  // MFMA C/D frag

__device__ __forceinline__ float bf2f(ushort u){
    union { unsigned int i; float f; } v; v.i = ((unsigned int)u) << 16; return v.f;
}
__device__ __forceinline__ ushort f2bf(float f){
    union { float f; unsigned int i; } v; v.f = f;
    unsigned int x = v.i;
    return (ushort)((x + 0x7FFFu + ((x >> 16) & 1u)) >> 16);  // RNE, inputs finite
}

// XCD schedule tables for the 256x256 kernel: g = kkidx*3 + nt (7 kk x 3 nt).
// Per-XCD sum(kk): {13,13,13,13,13,13,13,14} — balanced.
__device__ const int GCNT2[8] = {2,2,2,2,2,2,4,5};
__device__ const int GLIST2[8][5] = {
    {18, 9, 0, 0, 0},   // kk8/nt0 + kk5/nt0          = 13
    {19,10, 0, 0, 0},   // kk8/nt1 + kk5/nt1          = 13
    {20,11, 0, 0, 0},   // kk8/nt2 + kk5/nt2          = 13
    {15,12, 0, 0, 0},   // kk7/nt0 + kk6/nt0          = 13
    {16,13, 0, 0, 0},   // kk7/nt1 + kk6/nt1          = 13
    {17,14, 0, 0, 0},   // kk7/nt2 + kk6/nt2          = 13
    { 6, 7, 3, 0, 0},   // kk4/nt0 + kk4/nt1 + kk3/nt0 + kk2/nt0 = 13
    { 8, 4, 5, 1, 2},   // kk4/nt2 + kk3/nt1 + kk3/nt2 + kk2/nt1 + kk2/nt2 = 14
};

// ---------------------------------------------------------------------------
// Kernel 0: dtype detector (flag=1 -> bf16 data, flag=0 -> float32).
// ---------------------------------------------------------------------------
__global__ void detect_kernel(const unsigned int* __restrict__ feat_raw, int* __restrict__ flag){
    __shared__ int cnt_s;
    if (threadIdx.x == 0) cnt_s = 0;
    __syncthreads();
    int c = 0;
    for (int i = threadIdx.x; i < 4096; i += 256){
        unsigned int w = feat_raw[i];
        unsigned int e = (w >> 7) & 0xFFu;
        if (e >= 100u && e <= 150u) c++;
    }
    atomicAdd(&cnt_s, c);
    __syncthreads();
    if (threadIdx.x == 0) *flag = (cnt_s > 2457) ? 1 : 0;
}

// ---------------------------------------------------------------------------
// Kernel 1: per-batch span offsets. offs[b][0..8]; counts[k] = max(n-k-2, 0).
// ---------------------------------------------------------------------------
__global__ void offs_kernel(const int* __restrict__ mask, int* __restrict__ offs){
    int b = blockIdx.x;
    int lane = threadIdx.x;
    int s = 0;
    for (int i = lane; i < LL; i += 64) s += mask[b*LL + i];
    #pragma unroll
    for (int d = 32; d > 0; d >>= 1) s += __shfl_down(s, d, 64);
    if (lane == 0){
        int n = s, cum = 0;
        offs[b*9 + 0] = 0;
        for (int j = 0; j < 8; ++j){
            int c = n - j - 2; if (c < 0) c = 0;
            cum += c;
            offs[b*9 + j + 1] = cum;
        }
    }
}

// ---------------------------------------------------------------------------
// Kernel 1b: flattened-M row maps per width bucket.
// ---------------------------------------------------------------------------
__global__ void maps_kernel(const int* __restrict__ offs, int* __restrict__ pfx,
                            int* __restrict__ amap, int* __restrict__ omap){
    const int kkidx = blockIdx.x;
    const int kk = kkidx + 2;
    __shared__ int P[33];
    __shared__ int base_s[32];
    const int tid = threadIdx.x;
    if (tid == 0){
        int acc = 0; P[0] = 0;
        for (int b = 0; b < 32; ++b){
            acc += offs[b*9 + kk] - offs[b*9 + kk - 1];
            P[b+1] = acc;
        }
    }
    if (tid < 32) base_s[tid] = offs[tid*9 + kk - 1];
    __syncthreads();
    if (tid == 0) pfx[kkidx*33 + 32] = P[32];
    const int Mtot = P[32];
    for (int r = tid; r < MAXM; r += 256){
        int b = 0;
        #pragma unroll
        for (int i = 1; i <= 32; ++i) b += (P[i] <= r) ? 1 : 0;
        int bb = b < 32 ? b : 31;
        int larow = (r < Mtot) ? (r - P[bb]) : 0;   // clamp OOB rows to a safe row
        amap[kkidx*MAXM + r] = bb*LL + larow + 1;
        omap[kkidx*MAXM + r] = bb*SS + base_s[bb] + larow;
    }
}

// ---------------------------------------------------------------------------
// Kernel 2: ALL widths' weight repack in ONE launch. grid=(192, 7).
// ---------------------------------------------------------------------------
__global__ void repack2_kernel(const void* __restrict__ w2, const void* __restrict__ w3,
                               const void* __restrict__ w4, const void* __restrict__ w5,
                               const void* __restrict__ w6, const void* __restrict__ w7,
                               const void* __restrict__ w8,
                               const void* __restrict__ b2, const void* __restrict__ b3,
                               const void* __restrict__ b4, const void* __restrict__ b5,
                               const void* __restrict__ b6, const void* __restrict__ b7,
                               const void* __restrict__ b8,
                               ushort* __restrict__ BpAll, float* __restrict__ biasF,
                               const int* __restrict__ flag){
    const int kkidx = blockIdx.y;
    const int kk = kkidx + 2;
    const void* w  = kkidx==0?w2:kkidx==1?w3:kkidx==2?w4:kkidx==3?w5:kkidx==4?w6:kkidx==5?w7:w8;
    const void* bv = kkidx==0?b2:kkidx==1?b3:kkidx==2?b4:kkidx==3?b5:kkidx==4?b6:kkidx==5?b7:b8;
    ushort* Bp = BpAll + (size_t)(kkidx*(kkidx+3)/2)*589824;   // PRE[kkidx]

    const int bfm = *flag;
    __shared__ ushort lds[24576];         // 4 rows x 768*8 max (49152 B)
    const int tid = threadIdx.x;
    const int ob  = blockIdx.x;           // 4 output channels each
    const int rowlen = DD * kk;
    const int nelem  = 4 * rowlen;

    if (bfm){
        const ushort* src = (const ushort*)w + (size_t)ob * nelem;
        const int nch = nelem >> 3;
        for (int c = tid; c < nch; c += 256)
            __builtin_memcpy(lds + c*8, src + c*8, 16);
        if (ob == 0)
            for (int i = tid; i < DD; i += 256) biasF[kkidx*DD + i] = bf2f(((const ushort*)bv)[i]);
    } else {
        const float* src = (const float*)w + (size_t)ob * nelem;
        const int nch = nelem >> 2;
        for (int c = tid; c < nch; c += 256){
            float t4[4];
            __builtin_memcpy(t4, src + c*4, 16);
            #pragma unroll
            for (int j2 = 0; j2 < 4; ++j2) lds[c*4 + j2] = f2bf(t4[j2]);
        }
        if (ob == 0)
            for (int i = tid; i < DD; i += 256) biasF[kkidx*DD + i] = ((const float*)bv)[i];
    }
    __syncthreads();

    const int total = 96 * kk * 4;
    for (int c = tid; c < total; c += 256){
        int jb = c >> 2, ol = c & 3;
        int j0 = jb * 8;
        int t  = j0 / 768;
        int i0 = j0 - t * 768;
        ushort tmp[8];
        #pragma unroll
        for (int jj = 0; jj < 8; ++jj)
            tmp[jj] = lds[ol*rowlen + (i0 + jj)*kk + t];
        int o = ob*4 + ol;
        __builtin_memcpy(Bp + (size_t)jb*6144 + (size_t)o*8, tmp, 16);
    }
}

// ---------------------------------------------------------------------------
// Kernel 2b: features -> bf16 A-source buffer.
// ---------------------------------------------------------------------------
__global__ void cvtA_kernel(const void* __restrict__ feat, ushort* __restrict__ featbf,
                            const int* __restrict__ flag){
    const int bfm = *flag;
    int idx = blockIdx.x*256 + threadIdx.x;
    const int TOT = BB*LL*DD/8;
    if (idx >= TOT) return;
    if (bfm){
        __builtin_memcpy(featbf + (size_t)idx*8, (const ushort*)feat + (size_t)idx*8, 16);
    } else {
        float t8[8];
        __builtin_memcpy(t8,     (const float*)feat + (size_t)idx*8,     16);
        __builtin_memcpy(t8 + 4, (const float*)feat + (size_t)idx*8 + 4, 16);
        ushort o8[8];
        #pragma unroll
        for (int j = 0; j < 8; ++j) o8[j] = f2bf(t8[j]);
        __builtin_memcpy(featbf + (size_t)idx*8, o8, 16);
    }
}

// ---------------------------------------------------------------------------
// Kernel 3 (v2): unigram copy + zero invalid + valid flags.
// One (s,b) row per block; branch is BLOCK-UNIFORM (no divergence, no div/mod).
// ---------------------------------------------------------------------------
__global__ void fill2_kernel(const void* __restrict__ feat, const int* __restrict__ offs,
                             void* __restrict__ out, const int* __restrict__ flag){
    const int s = blockIdx.x;
    const int b = blockIdx.y;
    const int bfm = *flag;
    const int tid = threadIdx.x;
    const int c0  = offs[b*9 + 1];
    const int tot = offs[b*9 + 8];
    if (bfm){
        if (tid < 96){
            ushort* dst = (ushort*)out + ((size_t)b*SS + s)*768 + tid*8;
            if (s < c0){
                const ushort* srcp = (const ushort*)feat + ((size_t)b*LL + s + 1)*768 + tid*8;
                __builtin_memcpy(dst, srcp, 16);
            } else if (s >= tot){
                const ushort z[8] = {0,0,0,0,0,0,0,0};
                __builtin_memcpy(dst, z, 16);
            }
        } else if (tid == 96){
            ((ushort*)out)[(size_t)BB*SS*768 + (size_t)b*SS + s] = (s < tot) ? (ushort)0x3F80 : (ushort)0;
        }
    } else {
        if (tid < 192){
            float* dst = (float*)out + ((size_t)b*SS + s)*768 + tid*4;
            if (s < c0){
                const float* srcp = (const float*)feat + ((size_t)b*LL + s + 1)*768 + tid*4;
                __builtin_memcpy(dst, srcp, 16);
            } else if (s >= tot){
                const float z[4] = {0.f,0.f,0.f,0.f};
                __builtin_memcpy(dst, z, 16);
            }
        } else if (tid == 192){
            ((float*)out)[(size_t)BB*SS*768 + (size_t)b*SS + s] = (s < tot) ? 1.0f : 0.0f;
        }
    }
}

// ---------------------------------------------------------------------------
// Kernel 4 (v6): 256x256-tile GEMM, BK=32, 8 waves (4M x 2N), counted-vmcnt
// double-buffered pipeline (r4-proven). Issued bytes per FLOP halved vs the
// 128x128 tile: 32 KB per 4.2 MFLOP. LDS = 2 x (A 16KB + B 16KB) = 64 KB.
// All schedule variants measured the same ~7.9 TB/s issued-byte ceiling, so
// bytes — not schedule — set the time; this kernel cuts bytes 2x.
// ---------------------------------------------------------------------------
__global__ __launch_bounds__(512, 2) void conv_gemm7(const ushort* __restrict__ featbf,
        const ushort* __restrict__ BpAll, const float* __restrict__ biasF,
        const int* __restrict__ pfx, const int* __restrict__ amap,
        const int* __restrict__ omap, void* __restrict__ out,
        const int* __restrict__ flag){
    const int n   = blockIdx.x;
    const int xcd = n & 7;
    const int is  = n >> 3;
    const int cx  = GCNT2[xcd];
    if (is >= cx * 25) return;
    const int gi = is % cx;                // group-interleaved within XCD
    const int mt = is / cx;
    const int g  = GLIST2[xcd][gi];
    const int kkidx = g / 3;
    const int nt = g - kkidx*3;
    const int kk = kkidx + 2;
    const int Mtot = pfx[kkidx*33 + 32];
    const int m0 = mt * 256;
    if (m0 >= Mtot) return;
    const int n0 = nt * 256;
    const int bfm = *flag;

    __shared__ ushort LDSbuf[32768];       // 64 KB: 2 bufs x (A 16KB + B 16KB)

    const int tid  = threadIdx.x;          // 0..511
    const int wv   = tid >> 6;             // 0..7
    const int wvm  = wv >> 1;              // 0..3: rows m0 + wvm*64
    const int wvn  = wv & 1;               // 0..1: cols n0 + wvn*128
    const int lane = tid & 63;
    const int quad = lane >> 4;
    const int l15  = lane & 15;

    // A staging sources: j in {0,1}, segment g2 = j*8+wv encodes (wvm_s, sm_s):
    // lane (quad,l15) supplies featbf[amap(m0+wvm_s*64+sm_s*16+l15)][quad*8..+8]
    const ushort* srcA[2];
    #pragma unroll
    for (int j = 0; j < 2; ++j){
        int g2 = j*8 + wv;
        int rr = kkidx*MAXM + m0 + (g2 >> 2)*64 + (g2 & 3)*16 + l15;
        srcA[j] = featbf + (size_t)amap[rr]*768 + quad*8;
    }
    // B staging sources: slot c = j*512+tid -> plane c>>8 (0..3), col c&255
    const ushort* BkkBase = BpAll + (size_t)(kkidx*(kkidx+3)/2)*589824;
    const ushort* srcB[2];
    #pragma unroll
    for (int j = 0; j < 2; ++j){
        int c = j*512 + tid;
        srcB[j] = BkkBase + (size_t)(c >> 8)*6144 + (size_t)(n0 + (c & 255))*8;
    }

    floatx4 acc[4][8];
    #pragma unroll
    for (int sn = 0; sn < 8; ++sn){
        float bv = biasF[kkidx*768 + n0 + wvn*128 + sn*16 + l15];
        #pragma unroll
        for (int sm = 0; sm < 4; ++sm){
            acc[sm][sn][0] = bv; acc[sm][sn][1] = bv;
            acc[sm][sn][2] = bv; acc[sm][sn][3] = bv;
        }
    }

    char* lds0 = (char*)&LDSbuf[0];
    const int nchunks = kk * 24;           // K/32, always even (>=48)

    // STAGE: 4 gload_lds/thread. A chunk advance = ch*32 shorts (row-linear);
    // B chunk advance = ch*4 planes * 6144 shorts.
    #define STAGE(BUF, ch) do { \
        _Pragma("unroll") \
        for (int j_ = 0; j_ < 2; ++j_) \
            __builtin_amdgcn_global_load_lds( \
                (const __attribute__((address_space(1))) void*)(srcA[j_] + (ch)*32), \
                (__attribute__((address_space(3))) void*)(lds0 + (BUF)*32768 + (j_*512 + tid)*16), \
                16, 0, 0); \
        _Pragma("unroll") \
        for (int j_ = 0; j_ < 2; ++j_) \
            __builtin_amdgcn_global_load_lds( \
                (const __attribute__((address_space(1))) void*)(srcB[j_] + (size_t)(ch)*24576), \
                (__attribute__((address_space(3))) void*)(lds0 + (BUF)*32768 + 16384 + (j_*512 + tid)*16), \
                16, 0, 0); \
        } while(0)

    // COMPUTE: afr[sm] @ seg (wvm*4+sm)*1024 + lane*16 (lane-linear, no conflict)
    //          bfr[sn] @ 16384 + quad*4096 + (wvn*128+sn*16+l15)*16
    #define COMPUTE(BUF) do { \
        bf16x8 afr[4], bfr[8]; \
        _Pragma("unroll") \
        for (int sm_ = 0; sm_ < 4; ++sm_) \
            __builtin_memcpy(&afr[sm_], lds0 + (BUF)*32768 + (wvm*4 + sm_)*1024 + lane*16, 16); \
        _Pragma("unroll") \
        for (int sn_ = 0; sn_ < 8; ++sn_) \
            __builtin_memcpy(&bfr[sn_], lds0 + (BUF)*32768 + 16384 + quad*4096 + (wvn*128 + sn_*16 + l15)*16, 16); \
        __builtin_amdgcn_s_setprio(1); \
        _Pragma("unroll") \
        for (int sm_ = 0; sm_ < 4; ++sm_) \
            _Pragma("unroll") \
            for (int sn_ = 0; sn_ < 8; ++sn_) \
                acc[sm_][sn_] = __builtin_amdgcn_mfma_f32_16x16x32_bf16( \
                    afr[sm_], bfr[sn_], acc[sm_][sn_], 0, 0, 0); \
        __builtin_amdgcn_s_setprio(0); \
        } while(0)

    // Counted-vmcnt substep: stage next chunk (4 VMEM), wait for current
    // (vmcnt(4) keeps the next chunk in flight across both barriers).
    #define SUBSTEP(CH, CUR, NXT, DO, NW) do { \
        if (DO) STAGE(NXT, (CH)+1); \
        __builtin_amdgcn_sched_barrier(0); \
        asm volatile("s_waitcnt vmcnt(" NW ")" ::: "memory"); \
        __builtin_amdgcn_sched_barrier(0); \
        __builtin_amdgcn_s_barrier(); \
        __builtin_amdgcn_sched_barrier(0); \
        COMPUTE(CUR); \
        __builtin_amdgcn_s_barrier(); \
        __builtin_amdgcn_sched_barrier(0); \
    } while(0)

    STAGE(0, 0);                           // prologue: chunk 0 in flight
    for (int ch = 0; ch < nchunks - 2; ch += 2){
        SUBSTEP(ch,   0, 1, true, "4");
        SUBSTEP(ch+1, 1, 0, true, "4");
    }
    SUBSTEP(nchunks-2, 0, 1, true,  "4");
    SUBSTEP(nchunks-1, 1, 0, false, "0");

    #undef SUBSTEP
    #undef STAGE
    #undef COMPUTE

    // ---- epilogue: scatter rows to packed span slots ----
    #pragma unroll
    for (int sm = 0; sm < 4; ++sm){
        #pragma unroll
        for (int rr = 0; rr < 4; ++rr){
            int r2 = m0 + wvm*64 + sm*16 + quad*4 + rr;
            if (r2 < Mtot){
                int slot = omap[kkidx*MAXM + r2];
                if (bfm){
                    ushort* oh = (ushort*)out;
                    #pragma unroll
                    for (int sn = 0; sn < 8; ++sn)
                        oh[(size_t)slot*768 + n0 + wvn*128 + sn*16 + l15] = f2bf(acc[sm][sn][rr]);
                } else {
                    float* of = (float*)out;
                    #pragma unroll
                    for (int sn = 0; sn < 8; ++sn)
                        of[(size_t)slot*768 + n0 + wvn*128 + sn*16 + l15] = acc[sm][sn][rr];
                }
            }
        }
    }
}

// ---------------------------------------------------------------------------
// Fallback (workspace too small): direct-from-raw-weights GEMM. Slow, correct.
// ---------------------------------------------------------------------------
__global__ __launch_bounds__(256) void conv_gemm_direct(const void* __restrict__ feat,
        const int* __restrict__ offs, void* __restrict__ out, const int* __restrict__ flag,
        const void* w2, const void* w3, const void* w4, const void* w5,
        const void* w6, const void* w7, const void* w8,
        const void* b2, const void* b3, const void* b4, const void* b5,
        const void* b6, const void* b7, const void* b8){
    const int bfm = *flag;
    const int kkidx = blockIdx.y;
    const int kk = kkidx + 2;
    const int b = blockIdx.z;
    const void* w  = kkidx==0?w2:kkidx==1?w3:kkidx==2?w4:kkidx==3?w5:kkidx==4?w6:kkidx==5?w7:w8;
    const void* bv = kkidx==0?b2:kkidx==1?b3:kkidx==2?b4:kkidx==3?b5:kkidx==4?b6:kkidx==5?b7:b8;

    const int off_j = offs[b*9 + kk - 1];
    const int cnt   = offs[b*9 + kk] - off_j;
    const int mt = blockIdx.x / 12;
    const int nt = blockIdx.x - mt*12;
    const int m0 = mt * 64;
    if (m0 >= cnt) return;
    const int n0 = nt * 64;

    const int tid  = threadIdx.x;
    const int wvv  = tid >> 6;
    const int lane = tid & 63;
    const int quad = lane >> 4;
    const int l15  = lane & 15;

    int row  = m0 + wvv*16 + l15;
    int arow = row < cnt ? row : cnt - 1;
    const size_t abase = ((size_t)b*LL + arow + 1)*768 + quad*8;

    floatx4 acc[4];
    #pragma unroll
    for (int cg = 0; cg < 4; ++cg){
        float bb = bfm ? bf2f(((const ushort*)bv)[n0 + cg*16 + l15])
                       : ((const float*)bv)[n0 + cg*16 + l15];
        acc[cg][0] = bb; acc[cg][1] = bb; acc[cg][2] = bb; acc[cg][3] = bb;
    }

    const int steps = kk * 24;
    for (int s = 0; s < steps; ++s){
        bf16x8 a;
        if (bfm){
            __builtin_memcpy(&a, (const ushort*)feat + abase + s*32, 16);
        } else {
            float t8[8];
            __builtin_memcpy(t8,     (const float*)feat + abase + s*32,     16);
            __builtin_memcpy(t8 + 4, (const float*)feat + abase + s*32 + 4, 16);
            ushort o8[8];
            #pragma unroll
            for (int j = 0; j < 8; ++j) o8[j] = f2bf(t8[j]);
            __builtin_memcpy(&a, o8, 16);
        }
        int j0 = s*32 + quad*8;
        int t  = j0 / 768;
        int i0 = j0 - t*768;
        #pragma unroll
        for (int cg = 0; cg < 4; ++cg){
            int o = n0 + cg*16 + l15;
            size_t wbase = (size_t)o*(DD*kk) + (size_t)i0*kk + t;
            ushort tmp[8];
            if (bfm){
                const ushort* wp = (const ushort*)w + wbase;
                #pragma unroll
                for (int jj = 0; jj < 8; ++jj) tmp[jj] = wp[(size_t)jj*kk];
            } else {
                const float* wp = (const float*)w + wbase;
                #pragma unroll
                for (int jj = 0; jj < 8; ++jj) tmp[jj] = f2bf(wp[(size_t)jj*kk]);
            }
            bf16x8 bfr;
            __builtin_memcpy(&bfr, tmp, 16);
            acc[cg] = __builtin_amdgcn_mfma_f32_16x16x32_bf16(a, bfr, acc[cg], 0, 0, 0);
        }
    }

    const int rbase = m0 + wvv*16 + quad*4;
    if (bfm){
        ushort* outh = (ushort*)out;
        #pragma unroll
        for (int cg = 0; cg < 4; ++cg)
            #pragma unroll
            for (int rr = 0; rr < 4; ++rr){
                int grow = rbase + rr;
                if (grow < cnt)
                    outh[((size_t)b*SS + off_j + grow)*768 + n0 + cg*16 + l15] = f2bf(acc[cg][rr]);
            }
    } else {
        float* outf = (float*)out;
        #pragma unroll
        for (int cg = 0; cg < 4; ++cg)
            #pragma unroll
            for (int rr = 0; rr < 4; ++rr){
                int grow = rbase + rr;
                if (grow < cnt)
                    outf[((size_t)b*SS + off_j + grow)*768 + n0 + cg*16 + l15] = acc[cg][rr];
            }
    }
}

// ---------------------------------------------------------------------------
extern "C" void kernel_launch(void* const* d_in, const int* in_sizes, int n_in,
                              void* d_out, int out_size, void* d_ws, size_t ws_size,
                              hipStream_t stream) {
    const void* feat = d_in[0];
    const int*  mask = (const int*)d_in[1];

    const void* w[7]  = {0,0,0,0,0,0,0};
    const void* bs[7] = {0,0,0,0,0,0,0};
    int bi = 0;
    for (int i = 3; i < n_in; ++i){
        if (in_sizes[i] == 768){
            if (bi < 7) bs[bi++] = d_in[i];
        } else {
            int kk = in_sizes[i] / 589824;
            if (kk >= 2 && kk <= 8) w[kk-2] = d_in[i];
        }
    }

    // ws layout
    char* ws = (char*)d_ws;
    int*    flag    = (int*)ws;                       // @0
    int*    offs    = (int*)(ws + 64);                // 1152 B
    int*    pfx     = (int*)(ws + 2048);              // 924 B
    float*  biasF   = (float*)(ws + 4096);            // 21504 B
    int*    amap    = (int*)(ws + 28672);             // 7*6400*4 = 179200
    int*    omap    = (int*)(ws + 28672 + 179200);    // 179200 -> end 387072
    ushort* featbf  = (ushort*)(ws + 393216);         // 9,830,400
    ushort* Bp      = (ushort*)(ws + 393216 + 9830400); // 41,287,680
    const size_t FULL_BYTES = 393216ull + 9830400ull + 41287680ull;  // 51,511,296
    const bool use_full = ws_size >= FULL_BYTES;

    hipLaunchKernelGGL(detect_kernel, dim3(1), dim3(256), 0, stream,
                       (const unsigned int*)feat, flag);
    hipLaunchKernelGGL(offs_kernel, dim3(BB), dim3(64), 0, stream, mask, offs);

    if (use_full){
        hipLaunchKernelGGL(repack2_kernel, dim3(192, 7), dim3(256), 0, stream,
                           w[0], w[1], w[2], w[3], w[4], w[5], w[6],
                           bs[0], bs[1], bs[2], bs[3], bs[4], bs[5], bs[6],
                           Bp, biasF, flag);
        hipLaunchKernelGGL(cvtA_kernel, dim3(2400), dim3(256), 0, stream, feat, featbf, flag);
        hipLaunchKernelGGL(maps_kernel, dim3(7), dim3(256), 0, stream, offs, pfx, amap, omap);
    }

    hipLaunchKernelGGL(fill2_kernel, dim3(SS, BB), dim3(256), 0, stream,
                       feat, offs, d_out, flag);

    if (use_full){
        // 1D grid: 8 XCD classes x up to 5 groups x 25 mt slots
        hipLaunchKernelGGL(conv_gemm7, dim3(1000), dim3(512), 0, stream,
                           featbf, Bp, biasF, pfx, amap, omap, d_out, flag);
    } else {
        hipLaunchKernelGGL(conv_gemm_direct, dim3(48, 7, BB), dim3(256), 0, stream,
                           feat, offs, d_out, flag,
                           w[0], w[1], w[2], w[3], w[4], w[5], w[6],
                           bs[0], bs[1], bs[2], bs[3], bs[4], bs[5], bs[6]);
    }
}

// Round 7
// 494.890 us; speedup vs baseline: 1.2093x; 1.1394x over previous
//
#include <hip/hip_runtime.h>
#include <hip/hip_bf16.h>

#define BB 32
#define LL 200
#define DD 768
#define SS 1556
#define MAXM 6400   // per-kk flattened row capacity (25 tiles x 256 = 6400)

typedef __attribute__((ext_vector_type(8))) short bf16x8;   // 8 bf16 = 4 VGPRs (MFMA A/B frag)
typedef __attribute__((ext_vector_type(4))) float floatx4;  // MFMA C/D frag

__device__ __forceinline__ float bf2f(ushort u){
    union { unsigned int i; float f; } v; v.i = ((unsigned int)u) << 16; return v.f;
}
__device__ __forceinline__ ushort f2bf(float f){
    union { float f; unsigned int i; } v; v.f = f;
    unsigned int x = v.i;
    return (ushort)((x + 0x7FFFu + ((x >> 16) & 1u)) >> 16);  // RNE, inputs finite
}

// XCD schedule tables: g = kkidx*3 + nt (7 kk x 3 nt). Per-XCD sum(kk) 13..14.
__device__ const int GCNT2[8] = {2,2,2,2,2,2,4,5};
__device__ const int GLIST2[8][5] = {
    {18, 9, 0, 0, 0},   // kk8/nt0 + kk5/nt0
    {19,10, 0, 0, 0},   // kk8/nt1 + kk5/nt1
    {20,11, 0, 0, 0},   // kk8/nt2 + kk5/nt2
    {15,12, 0, 0, 0},   // kk7/nt0 + kk6/nt0
    {16,13, 0, 0, 0},   // kk7/nt1 + kk6/nt1
    {17,14, 0, 0, 0},   // kk7/nt2 + kk6/nt2
    { 6, 7, 3, 0, 0},   // kk4 x2 + kk3
    { 8, 4, 5, 1, 2},   // kk4 + kk3 x2 + kk2 x2
};

// ---------------------------------------------------------------------------
// prep1: block 0 = dtype detect (flag), blocks 1..32 = per-batch span offsets.
// ---------------------------------------------------------------------------
__global__ void prep1_kernel(const unsigned int* __restrict__ feat_raw,
                             const int* __restrict__ mask,
                             int* __restrict__ flag, int* __restrict__ offs){
    __shared__ int cnt_s;
    const int bx = blockIdx.x;
    const int tid = threadIdx.x;
    if (bx == 0){
        if (tid == 0) cnt_s = 0;
        __syncthreads();
        int c = 0;
        for (int i = tid; i < 4096; i += 256){
            unsigned int w = feat_raw[i];
            unsigned int e = (w >> 7) & 0xFFu;
            if (e >= 100u && e <= 150u) c++;
        }
        atomicAdd(&cnt_s, c);
        __syncthreads();
        if (tid == 0) *flag = (cnt_s > 2457) ? 1 : 0;
    } else {
        const int b = bx - 1;
        if (tid < 64){
            int s = 0;
            for (int i = tid; i < LL; i += 64) s += mask[b*LL + i];
            #pragma unroll
            for (int d = 32; d > 0; d >>= 1) s += __shfl_down(s, d, 64);
            if (tid == 0){
                int n = s, cum = 0;
                offs[b*9 + 0] = 0;
                for (int j = 0; j < 8; ++j){
                    int c2 = n - j - 2; if (c2 < 0) c2 = 0;
                    cum += c2;
                    offs[b*9 + j + 1] = cum;
                }
            }
        }
    }
}

// ---------------------------------------------------------------------------
// prep2: fused {weight repack | feature->bf16 | row maps | unigram fill}.
// blockIdx partition: [0,1344) repack, [1344,2544) cvtA, [2544,2551) maps,
// rest = flat grid-stride fill.  full=0 -> fill only (fallback path).
// ---------------------------------------------------------------------------
__global__ void prep2_kernel(const void* __restrict__ feat, const int* __restrict__ offs,
        const int* __restrict__ flag,
        const void* w2, const void* w3, const void* w4, const void* w5,
        const void* w6, const void* w7, const void* w8,
        const void* b2, const void* b3, const void* b4, const void* b5,
        const void* b6, const void* b7, const void* b8,
        ushort* __restrict__ BpAll, float* __restrict__ biasF,
        ushort* __restrict__ featbf, int* __restrict__ pfx,
        int* __restrict__ amap, int* __restrict__ omap,
        void* __restrict__ out, int full){
    __shared__ ushort lds[24576];          // repack staging (49152 B)
    __shared__ int P[33];
    __shared__ int base_s[32];
    const int tid = threadIdx.x;
    const int bx  = blockIdx.x;
    const int bfm = *flag;
    const int repN = full ? 1344 : 0;
    const int cvtN = full ? 1200 : 0;
    const int mapN = full ? 7 : 0;

    if (bx < repN){
        // ---- weight repack: bx = kkidx*192 + ob ----
        const int kkidx = bx / 192;
        const int ob    = bx - kkidx*192;
        const int kk    = kkidx + 2;
        const void* w  = kkidx==0?w2:kkidx==1?w3:kkidx==2?w4:kkidx==3?w5:kkidx==4?w6:kkidx==5?w7:w8;
        const void* bv = kkidx==0?b2:kkidx==1?b3:kkidx==2?b4:kkidx==3?b5:kkidx==4?b6:kkidx==5?b7:b8;
        ushort* Bp = BpAll + (size_t)(kkidx*(kkidx+3)/2)*589824;
        const int rowlen = DD * kk;
        const int nelem  = 4 * rowlen;
        if (bfm){
            const ushort* src = (const ushort*)w + (size_t)ob * nelem;
            const int nch = nelem >> 3;
            for (int c = tid; c < nch; c += 256)
                __builtin_memcpy(lds + c*8, src + c*8, 16);
            if (ob == 0)
                for (int i = tid; i < DD; i += 256) biasF[kkidx*DD + i] = bf2f(((const ushort*)bv)[i]);
        } else {
            const float* src = (const float*)w + (size_t)ob * nelem;
            const int nch = nelem >> 2;
            for (int c = tid; c < nch; c += 256){
                float t4[4];
                __builtin_memcpy(t4, src + c*4, 16);
                #pragma unroll
                for (int j2 = 0; j2 < 4; ++j2) lds[c*4 + j2] = f2bf(t4[j2]);
            }
            if (ob == 0)
                for (int i = tid; i < DD; i += 256) biasF[kkidx*DD + i] = ((const float*)bv)[i];
        }
        __syncthreads();
        const int total = 96 * kk * 4;
        for (int c = tid; c < total; c += 256){
            int jb = c >> 2, ol = c & 3;
            int j0 = jb * 8;
            int t  = j0 / 768;
            int i0 = j0 - t * 768;
            ushort tmp[8];
            #pragma unroll
            for (int jj = 0; jj < 8; ++jj)
                tmp[jj] = lds[ol*rowlen + (i0 + jj)*kk + t];
            int o = ob*4 + ol;
            __builtin_memcpy(Bp + (size_t)jb*6144 + (size_t)o*8, tmp, 16);
        }
    } else if (bx < repN + cvtN){
        // ---- features -> bf16 A-source (grid-stride, 2 iters) ----
        const int TOT = BB*LL*DD/8;        // 614400
        for (int idx = (bx - repN)*256 + tid; idx < TOT; idx += cvtN*256){
            if (bfm){
                __builtin_memcpy(featbf + (size_t)idx*8, (const ushort*)feat + (size_t)idx*8, 16);
            } else {
                float t8[8];
                __builtin_memcpy(t8,     (const float*)feat + (size_t)idx*8,     16);
                __builtin_memcpy(t8 + 4, (const float*)feat + (size_t)idx*8 + 4, 16);
                ushort o8[8];
                #pragma unroll
                for (int j = 0; j < 8; ++j) o8[j] = f2bf(t8[j]);
                __builtin_memcpy(featbf + (size_t)idx*8, o8, 16);
            }
        }
    } else if (bx < repN + cvtN + mapN){
        // ---- flattened-M row maps ----
        const int kkidx = bx - (repN + cvtN);
        const int kk = kkidx + 2;
        if (tid == 0){
            int acc = 0; P[0] = 0;
            for (int b = 0; b < 32; ++b){
                acc += offs[b*9 + kk] - offs[b*9 + kk - 1];
                P[b+1] = acc;
            }
        }
        if (tid < 32) base_s[tid] = offs[tid*9 + kk - 1];
        __syncthreads();
        if (tid == 0) pfx[kkidx*33 + 32] = P[32];
        const int Mtot = P[32];
        for (int r = tid; r < MAXM; r += 256){
            int b = 0;
            #pragma unroll
            for (int i = 1; i <= 32; ++i) b += (P[i] <= r) ? 1 : 0;
            int bb = b < 32 ? b : 31;
            int larow = (r < Mtot) ? (r - P[bb]) : 0;
            amap[kkidx*MAXM + r] = bb*LL + larow + 1;
            omap[kkidx*MAXM + r] = bb*SS + base_s[bb] + larow;
        }
    } else {
        // ---- flat grid-stride fill: unigram copy + zeros + valid flags ----
        const int fb = bx - (repN + cvtN + mapN);   // 0..2047
        if (bfm){
            const int TOTC = BB*SS*96;
            for (int idx = fb*256 + tid; idx < TOTC; idx += 2048*256){
                int r  = idx / 96;
                int c  = idx - r*96;
                int b  = r / SS;
                int s  = r - b*SS;
                int c0  = offs[b*9 + 1];
                int tot = offs[b*9 + 8];
                ushort* dst = (ushort*)out + ((size_t)r)*768 + c*8;
                if (s < c0){
                    const ushort* srcp = (const ushort*)feat + ((size_t)b*LL + s + 1)*768 + c*8;
                    __builtin_memcpy(dst, srcp, 16);
                } else if (s >= tot){
                    const ushort z[8] = {0,0,0,0,0,0,0,0};
                    __builtin_memcpy(dst, z, 16);
                }
                if (c == 0)
                    ((ushort*)out)[(size_t)BB*SS*768 + (size_t)b*SS + s] = (s < tot) ? (ushort)0x3F80 : (ushort)0;
            }
        } else {
            const int TOTC = BB*SS*192;
            for (int idx = fb*256 + tid; idx < TOTC; idx += 2048*256){
                int r  = idx / 192;
                int c  = idx - r*192;
                int b  = r / SS;
                int s  = r - b*SS;
                int c0  = offs[b*9 + 1];
                int tot = offs[b*9 + 8];
                float* dst = (float*)out + ((size_t)r)*768 + c*4;
                if (s < c0){
                    const float* srcp = (const float*)feat + ((size_t)b*LL + s + 1)*768 + c*4;
                    __builtin_memcpy(dst, srcp, 16);
                } else if (s >= tot){
                    const float z[4] = {0.f,0.f,0.f,0.f};
                    __builtin_memcpy(dst, z, 16);
                }
                if (c == 0)
                    ((float*)out)[(size_t)BB*SS*768 + (size_t)b*SS + s] = (s < tot) ? 1.0f : 0.0f;
            }
        }
    }
}

// ---------------------------------------------------------------------------
// conv (v7): 256x256 tile, BK=32, **16 waves (1024 thr, 4m x 4n, 64x64/wave)**.
// Same counted-vmcnt double-buffer as r6, but 4 waves/SIMD give the TLP that
// the 8-wave version lacked (r6: 3250 cyc/chunk vs ~1250 floor, MfmaUtil 21%).
// acc = 64 regs/wave -> fits the 128-reg budget 1024-thread blocks require.
// ---------------------------------------------------------------------------
__global__ __launch_bounds__(1024) void conv_gemm8(const ushort* __restrict__ featbf,
        const ushort* __restrict__ BpAll, const float* __restrict__ biasF,
        const int* __restrict__ pfx, const int* __restrict__ amap,
        const int* __restrict__ omap, void* __restrict__ out,
        const int* __restrict__ flag){
    const int n   = blockIdx.x;
    const int xcd = n & 7;
    const int is  = n >> 3;
    const int cx  = GCNT2[xcd];
    if (is >= cx * 25) return;
    const int gi = is % cx;
    const int mt = is / cx;
    const int g  = GLIST2[xcd][gi];
    const int kkidx = g / 3;
    const int nt = g - kkidx*3;
    const int kk = kkidx + 2;
    const int Mtot = pfx[kkidx*33 + 32];
    const int m0 = mt * 256;
    if (m0 >= Mtot) return;
    const int n0 = nt * 256;
    const int bfm = *flag;

    __shared__ ushort LDSbuf[32768];       // 64 KB: 2 bufs x (A 16KB + B 16KB)

    const int tid  = threadIdx.x;          // 0..1023
    const int wv   = tid >> 6;             // 0..15
    const int wvm  = wv >> 2;              // 0..3: rows m0 + wvm*64
    const int wvn  = wv & 3;               // 0..3: cols n0 + wvn*64
    const int lane = tid & 63;
    const int quad = lane >> 4;
    const int l15  = lane & 15;

    // A staging: wave w stages seg w = rows m0+w*16+l15, k-part quad*8.
    const ushort* srcA = featbf + (size_t)amap[kkidx*MAXM + m0 + wv*16 + l15]*768 + quad*8;
    // B staging: wave w covers slots [w*64,(w+1)*64): plane w>>2, col n0+(w&3)*64+lane.
    const ushort* BkkBase = BpAll + (size_t)(kkidx*(kkidx+3)/2)*589824;
    const ushort* srcB = BkkBase + (size_t)(wv >> 2)*6144 + (size_t)(n0 + (wv & 3)*64 + lane)*8;

    char* lds0 = (char*)&LDSbuf[0];
    const int dstA = wv*1024;              // wave-uniform byte base (+ lane*16 by HW)
    const int dstB = 16384 + wv*1024;

    floatx4 acc[4][4];
    #pragma unroll
    for (int sn = 0; sn < 4; ++sn){
        float bv = biasF[kkidx*768 + n0 + wvn*64 + sn*16 + l15];
        #pragma unroll
        for (int sm = 0; sm < 4; ++sm){
            acc[sm][sn][0] = bv; acc[sm][sn][1] = bv;
            acc[sm][sn][2] = bv; acc[sm][sn][3] = bv;
        }
    }

    const int nchunks = kk * 24;           // K/32, always even

    #define STAGE(BUF, ch) do { \
        __builtin_amdgcn_global_load_lds( \
            (const __attribute__((address_space(1))) void*)(srcA + (ch)*32), \
            (__attribute__((address_space(3))) void*)(lds0 + (BUF)*32768 + dstA), \
            16, 0, 0); \
        __builtin_amdgcn_global_load_lds( \
            (const __attribute__((address_space(1))) void*)(srcB + (size_t)(ch)*24576), \
            (__attribute__((address_space(3))) void*)(lds0 + (BUF)*32768 + dstB), \
            16, 0, 0); \
        } while(0)

    // afr[sm]: seg (wvm*4+sm), lane-linear. bfr[sn]: plane quad, col wvn*64+sn*16+l15.
    #define COMPUTE(BUF) do { \
        bf16x8 afr[4], bfr[4]; \
        _Pragma("unroll") \
        for (int sm_ = 0; sm_ < 4; ++sm_) \
            __builtin_memcpy(&afr[sm_], lds0 + (BUF)*32768 + (wvm*4 + sm_)*1024 + lane*16, 16); \
        _Pragma("unroll") \
        for (int sn_ = 0; sn_ < 4; ++sn_) \
            __builtin_memcpy(&bfr[sn_], lds0 + (BUF)*32768 + 16384 + quad*4096 + (wvn*64 + sn_*16 + l15)*16, 16); \
        __builtin_amdgcn_s_setprio(1); \
        _Pragma("unroll") \
        for (int sm_ = 0; sm_ < 4; ++sm_) \
            _Pragma("unroll") \
            for (int sn_ = 0; sn_ < 4; ++sn_) \
                acc[sm_][sn_] = __builtin_amdgcn_mfma_f32_16x16x32_bf16( \
                    afr[sm_], bfr[sn_], acc[sm_][sn_], 0, 0, 0); \
        __builtin_amdgcn_s_setprio(0); \
        } while(0)

    #define SUBSTEP(CH, CUR, NXT, DO, NW) do { \
        if (DO) STAGE(NXT, (CH)+1); \
        __builtin_amdgcn_sched_barrier(0); \
        asm volatile("s_waitcnt vmcnt(" NW ")" ::: "memory"); \
        __builtin_amdgcn_sched_barrier(0); \
        __builtin_amdgcn_s_barrier(); \
        __builtin_amdgcn_sched_barrier(0); \
        COMPUTE(CUR); \
        __builtin_amdgcn_s_barrier(); \
        __builtin_amdgcn_sched_barrier(0); \
    } while(0)

    STAGE(0, 0);                           // prologue: chunk 0 (2 loads) in flight
    for (int ch = 0; ch < nchunks - 2; ch += 2){
        SUBSTEP(ch,   0, 1, true, "2");
        SUBSTEP(ch+1, 1, 0, true, "2");
    }
    SUBSTEP(nchunks-2, 0, 1, true,  "2");
    SUBSTEP(nchunks-1, 1, 0, false, "0");

    #undef SUBSTEP
    #undef STAGE
    #undef COMPUTE

    // ---- epilogue: scatter rows to packed span slots ----
    #pragma unroll
    for (int sm = 0; sm < 4; ++sm){
        #pragma unroll
        for (int rr = 0; rr < 4; ++rr){
            int r2 = m0 + wvm*64 + sm*16 + quad*4 + rr;
            if (r2 < Mtot){
                int slot = omap[kkidx*MAXM + r2];
                if (bfm){
                    ushort* oh = (ushort*)out;
                    #pragma unroll
                    for (int sn = 0; sn < 4; ++sn)
                        oh[(size_t)slot*768 + n0 + wvn*64 + sn*16 + l15] = f2bf(acc[sm][sn][rr]);
                } else {
                    float* of = (float*)out;
                    #pragma unroll
                    for (int sn = 0; sn < 4; ++sn)
                        of[(size_t)slot*768 + n0 + wvn*64 + sn*16 + l15] = acc[sm][sn][rr];
                }
            }
        }
    }
}

// ---------------------------------------------------------------------------
// Fallback (workspace too small): direct-from-raw-weights GEMM. Slow, correct.
// ---------------------------------------------------------------------------
__global__ __launch_bounds__(256) void conv_gemm_direct(const void* __restrict__ feat,
        const int* __restrict__ offs, void* __restrict__ out, const int* __restrict__ flag,
        const void* w2, const void* w3, const void* w4, const void* w5,
        const void* w6, const void* w7, const void* w8,
        const void* b2, const void* b3, const void* b4, const void* b5,
        const void* b6, const void* b7, const void* b8){
    const int bfm = *flag;
    const int kkidx = blockIdx.y;
    const int kk = kkidx + 2;
    const int b = blockIdx.z;
    const void* w  = kkidx==0?w2:kkidx==1?w3:kkidx==2?w4:kkidx==3?w5:kkidx==4?w6:kkidx==5?w7:w8;
    const void* bv = kkidx==0?b2:kkidx==1?b3:kkidx==2?b4:kkidx==3?b5:kkidx==4?b6:kkidx==5?b7:b8;

    const int off_j = offs[b*9 + kk - 1];
    const int cnt   = offs[b*9 + kk] - off_j;
    const int mt = blockIdx.x / 12;
    const int nt = blockIdx.x - mt*12;
    const int m0 = mt * 64;
    if (m0 >= cnt) return;
    const int n0 = nt * 64;

    const int tid  = threadIdx.x;
    const int wvv  = tid >> 6;
    const int lane = tid & 63;
    const int quad = lane >> 4;
    const int l15  = lane & 15;

    int row  = m0 + wvv*16 + l15;
    int arow = row < cnt ? row : cnt - 1;
    const size_t abase = ((size_t)b*LL + arow + 1)*768 + quad*8;

    floatx4 acc[4];
    #pragma unroll
    for (int cg = 0; cg < 4; ++cg){
        float bb = bfm ? bf2f(((const ushort*)bv)[n0 + cg*16 + l15])
                       : ((const float*)bv)[n0 + cg*16 + l15];
        acc[cg][0] = bb; acc[cg][1] = bb; acc[cg][2] = bb; acc[cg][3] = bb;
    }

    const int steps = kk * 24;
    for (int s = 0; s < steps; ++s){
        bf16x8 a;
        if (bfm){
            __builtin_memcpy(&a, (const ushort*)feat + abase + s*32, 16);
        } else {
            float t8[8];
            __builtin_memcpy(t8,     (const float*)feat + abase + s*32,     16);
            __builtin_memcpy(t8 + 4, (const float*)feat + abase + s*32 + 4, 16);
            ushort o8[8];
            #pragma unroll
            for (int j = 0; j < 8; ++j) o8[j] = f2bf(t8[j]);
            __builtin_memcpy(&a, o8, 16);
        }
        int j0 = s*32 + quad*8;
        int t  = j0 / 768;
        int i0 = j0 - t*768;
        #pragma unroll
        for (int cg = 0; cg < 4; ++cg){
            int o = n0 + cg*16 + l15;
            size_t wbase = (size_t)o*(DD*kk) + (size_t)i0*kk + t;
            ushort tmp[8];
            if (bfm){
                const ushort* wp = (const ushort*)w + wbase;
                #pragma unroll
                for (int jj = 0; jj < 8; ++jj) tmp[jj] = wp[(size_t)jj*kk];
            } else {
                const float* wp = (const float*)w + wbase;
                #pragma unroll
                for (int jj = 0; jj < 8; ++jj) tmp[jj] = f2bf(wp[(size_t)jj*kk]);
            }
            bf16x8 bfr;
            __builtin_memcpy(&bfr, tmp, 16);
            acc[cg] = __builtin_amdgcn_mfma_f32_16x16x32_bf16(a, bfr, acc[cg], 0, 0, 0);
        }
    }

    const int rbase = m0 + wvv*16 + quad*4;
    if (bfm){
        ushort* outh = (ushort*)out;
        #pragma unroll
        for (int cg = 0; cg < 4; ++cg)
            #pragma unroll
            for (int rr = 0; rr < 4; ++rr){
                int grow = rbase + rr;
                if (grow < cnt)
                    outh[((size_t)b*SS + off_j + grow)*768 + n0 + cg*16 + l15] = f2bf(acc[cg][rr]);
            }
    } else {
        float* outf = (float*)out;
        #pragma unroll
        for (int cg = 0; cg < 4; ++cg)
            #pragma unroll
            for (int rr = 0; rr < 4; ++rr){
                int grow = rbase + rr;
                if (grow < cnt)
                    outf[((size_t)b*SS + off_j + grow)*768 + n0 + cg*16 + l15] = acc[cg][rr];
            }
    }
}

// ---------------------------------------------------------------------------
extern "C" void kernel_launch(void* const* d_in, const int* in_sizes, int n_in,
                              void* d_out, int out_size, void* d_ws, size_t ws_size,
                              hipStream_t stream) {
    const void* feat = d_in[0];
    const int*  mask = (const int*)d_in[1];

    const void* w[7]  = {0,0,0,0,0,0,0};
    const void* bs[7] = {0,0,0,0,0,0,0};
    int bi = 0;
    for (int i = 3; i < n_in; ++i){
        if (in_sizes[i] == 768){
            if (bi < 7) bs[bi++] = d_in[i];
        } else {
            int kk = in_sizes[i] / 589824;
            if (kk >= 2 && kk <= 8) w[kk-2] = d_in[i];
        }
    }

    // ws layout
    char* ws = (char*)d_ws;
    int*    flag    = (int*)ws;                       // @0
    int*    offs    = (int*)(ws + 64);                // 1152 B
    int*    pfx     = (int*)(ws + 2048);              // 924 B
    float*  biasF   = (float*)(ws + 4096);            // 21504 B
    int*    amap    = (int*)(ws + 28672);             // 7*6400*4 = 179200
    int*    omap    = (int*)(ws + 28672 + 179200);    // 179200 -> end 387072
    ushort* featbf  = (ushort*)(ws + 393216);         // 9,830,400
    ushort* Bp      = (ushort*)(ws + 393216 + 9830400); // 41,287,680
    const size_t FULL_BYTES = 393216ull + 9830400ull + 41287680ull;  // 51,511,296
    const bool use_full = ws_size >= FULL_BYTES;

    hipLaunchKernelGGL(prep1_kernel, dim3(33), dim3(256), 0, stream,
                       (const unsigned int*)feat, mask, flag, offs);

    if (use_full){
        // fused prep: 1344 repack + 1200 cvtA + 7 maps + 2048 fill = 4599 blocks
        hipLaunchKernelGGL(prep2_kernel, dim3(4599), dim3(256), 0, stream,
                           feat, offs, flag,
                           w[0], w[1], w[2], w[3], w[4], w[5], w[6],
                           bs[0], bs[1], bs[2], bs[3], bs[4], bs[5], bs[6],
                           Bp, biasF, featbf, pfx, amap, omap, d_out, 1);
        hipLaunchKernelGGL(conv_gemm8, dim3(1000), dim3(1024), 0, stream,
                           featbf, Bp, biasF, pfx, amap, omap, d_out, flag);
    } else {
        hipLaunchKernelGGL(prep2_kernel, dim3(2048), dim3(256), 0, stream,
                           feat, offs, flag,
                           w[0], w[1], w[2], w[3], w[4], w[5], w[6],
                           bs[0], bs[1], bs[2], bs[3], bs[4], bs[5], bs[6],
                           Bp, biasF, featbf, pfx, amap, omap, d_out, 0);
        hipLaunchKernelGGL(conv_gemm_direct, dim3(48, 7, BB), dim3(256), 0, stream,
                           feat, offs, d_out, flag,
                           w[0], w[1], w[2], w[3], w[4], w[5], w[6],
                           bs[0], bs[1], bs[2], bs[3], bs[4], bs[5], bs[6]);
    }
}